// Round 1
// 1582.525 us; speedup vs baseline: 1.1890x; 1.1890x over previous
//
#include <hip/hip_runtime.h>
#include <hip/hip_bf16.h>
#include <stdint.h>
#include <type_traits>

typedef __hip_bfloat16 hbf16;
typedef short bf16x8 __attribute__((ext_vector_type(8)));
typedef float f32x4 __attribute__((ext_vector_type(4)));

#define MFMA16(a, b, c) __builtin_amdgcn_mfma_f32_16x16x32_bf16((a), (b), (c), 0, 0, 0)

__device__ __forceinline__ void gload_lds16(const void* g, void* l) {
  __builtin_amdgcn_global_load_lds(
      (const __attribute__((address_space(1))) void*)g,
      (__attribute__((address_space(3))) void*)l, 16, 0, 0);
}

__device__ __forceinline__ float b2f(unsigned short u) {
  union { unsigned int u32; float f; } cv;
  cv.u32 = ((unsigned int)u) << 16;
  return cv.f;
}
__device__ __forceinline__ unsigned short f2b(float f) {
  hbf16 h = __float2bfloat16(f);
  return __builtin_bit_cast(unsigned short, h);
}

// element-index XOR swizzle for 64-col bf16 LDS tiles (attn kernels)
__device__ __forceinline__ int swz(int row, int col) {
  return row * 64 + (col ^ ((row & 7) << 3));
}

// ---------------------------------------------------------------------------
// fp32 -> bf16 conversion. n must be a multiple of 8.
// ---------------------------------------------------------------------------
__global__ __launch_bounds__(256) void cvt_f32_bf16(
    const float* __restrict__ src, unsigned short* __restrict__ dst, long long n)
{
  const long long i0 = ((long long)blockIdx.x * 256 + threadIdx.x) * 8;
  const long long stride = (long long)gridDim.x * 2048;
  for (long long i = i0; i < n; i += stride) {
    const float4 a = *(const float4*)(src + i);
    const float4 b = *(const float4*)(src + i + 4);
    bf16x8 o;
    o[0] = (short)f2b(a.x); o[1] = (short)f2b(a.y);
    o[2] = (short)f2b(a.z); o[3] = (short)f2b(a.w);
    o[4] = (short)f2b(b.x); o[5] = (short)f2b(b.y);
    o[6] = (short)f2b(b.z); o[7] = (short)f2b(b.w);
    *(bf16x8*)(dst + i) = o;
  }
}

// ---------------------------------------------------------------------------
// C[M,N] = A[M,K] @ W[N,K]^T (+bias), bf16 in, fp32 accum, OutT out.
// 256x256 tile, BK=32, 512 threads (8 waves as 2x4, each owning 128x64 of C).
// 4-deep LDS ring (128 KiB), depth-3 prefetch via global_load_lds, counted
// vmcnt(8) + ONE raw s_barrier per K-step (T3/T4). LDS chunk-XOR swizzle with
// pre-swizzled GLOBAL source (linear LDS dest; rule 21) makes every
// ds_read_b128 fragment read bank-conflict-free (T2). setprio around the
// 32-MFMA cluster (T5). Bijective XCD-chunked blockIdx remap, column-fast
// so each XCD's concurrent blocks share 8 A-panels (4 MB -> L2) (T1).
// Requires: M%256==0, N%256==0, K%32==0, K>=128, grid=(M/256)*(N/256)%8==0.
// ---------------------------------------------------------------------------
template <typename OutT>
__global__ __launch_bounds__(512, 2) void gemm_bt(
    const unsigned short* __restrict__ A,
    const unsigned short* __restrict__ W,
    const float* __restrict__ bias,
    OutT* __restrict__ C,
    int M, int N, int K)
{
  __shared__ __attribute__((aligned(16))) unsigned short As[4][8192];
  __shared__ __attribute__((aligned(16))) unsigned short Bs[4][8192];

  const int tid   = threadIdx.x;
  const int lane  = tid & 63;
  const int w     = tid >> 6;           // 0..7
  const int wr128 = (w >> 2) * 128;     // wave row offset in tile
  const int wn64  = (w & 3) * 64;       // wave col offset in tile
  const int lr    = lane & 15;
  const int lg    = lane >> 4;          // k-quarter
  const int wofs  = w * 512;            // elements: wave's linear staging slot

  // T1: bijective XCD-chunked remap; logical id is column-fast.
  const int nwg     = gridDim.x;
  const int bx      = blockIdx.x;
  const int logical = (bx & 7) * (nwg >> 3) + (bx >> 3);
  const int colsN   = N >> 8;
  const int tileM   = logical / colsN;
  const int tileN   = logical - tileM * colsN;
  const size_t rowBase = (size_t)tileM * 256;
  const int    colBase = tileN * 256;

  // Staging map: thread deposits 16B at linear LDS byte tid*16 (+8192 for the
  // second half) = (row = tid/4 + 128c, chunk = tid&3). To realize the
  // swizzle chunk' = chunk ^ ((row>>1)&3) with a LINEAR LDS dest, fetch the
  // inverse-swizzled global chunk. ((row>>1)&3) == ((tid>>3)&3) for both c.
  const int sRow   = tid >> 2;                       // 0..127
  const int sChunk = (tid & 3) ^ ((tid >> 3) & 3);
  const unsigned short* Ag0 = A + (rowBase + sRow) * (size_t)K + sChunk * 8;
  const unsigned short* Ag1 = Ag0 + (size_t)128 * K;
  const unsigned short* Wg0 = W + ((size_t)colBase + sRow) * K + sChunk * 8;
  const unsigned short* Wg1 = Wg0 + (size_t)128 * K;

  f32x4 acc[8][4] = {};

  const int nt = K >> 5;  // K-steps of 32

  // Prologue: stage tiles 0,1,2 (4 gload_lds each -> 12 in flight).
#pragma unroll
  for (int p = 0; p < 3; ++p) {
    const size_t ke = (size_t)p * 32;
    gload_lds16(Ag0 + ke, &As[p][0] + wofs);
    gload_lds16(Ag1 + ke, &As[p][0] + wofs + 4096);
    gload_lds16(Wg0 + ke, &Bs[p][0] + wofs);
    gload_lds16(Wg1 + ke, &Bs[p][0] + wofs + 4096);
  }

  // Per K-step: wait own tile-t loads (leave 2 tiles = 8 in flight), barrier
  // (=> ALL waves' tile-t loads landed, all tile-(t-1) reads done), ds_read
  // 12 swizzled fragments, issue tile-(t+3) stage into the buffer freed at
  // the barrier, then 32 MFMAs under setprio.
#define GITER(T, VM, STG)                                                     \
  do {                                                                        \
    asm volatile("s_waitcnt vmcnt(" VM ")" ::: "memory");                     \
    __builtin_amdgcn_s_barrier();                                             \
    __builtin_amdgcn_sched_barrier(0);                                        \
    const unsigned short* asb = &As[(T) & 3][0];                              \
    const unsigned short* bsb = &Bs[(T) & 3][0];                              \
    bf16x8 af[8];                                                             \
    bf16x8 bfv[4];                                                            \
    _Pragma("unroll")                                                         \
    for (int mi = 0; mi < 8; ++mi) {                                          \
      const int row = wr128 + mi * 16 + lr;                                   \
      af[mi] = *(const bf16x8*)(asb + row * 32 + (lg ^ ((row >> 1) & 3)) * 8);\
    }                                                                         \
    _Pragma("unroll")                                                         \
    for (int ni = 0; ni < 4; ++ni) {                                          \
      const int row = wn64 + ni * 16 + lr;                                    \
      bfv[ni] = *(const bf16x8*)(bsb + row * 32 + (lg ^ ((row >> 1) & 3)) * 8);\
    }                                                                         \
    if (STG) {                                                                \
      const size_t ke = (size_t)((T) + 3) * 32;                               \
      const int nb = ((T) + 3) & 3;                                           \
      gload_lds16(Ag0 + ke, &As[nb][0] + wofs);                               \
      gload_lds16(Ag1 + ke, &As[nb][0] + wofs + 4096);                        \
      gload_lds16(Wg0 + ke, &Bs[nb][0] + wofs);                               \
      gload_lds16(Wg1 + ke, &Bs[nb][0] + wofs + 4096);                        \
    }                                                                         \
    __builtin_amdgcn_s_setprio(1);                                            \
    _Pragma("unroll")                                                         \
    for (int mi = 0; mi < 8; ++mi)                                            \
      _Pragma("unroll")                                                       \
      for (int ni = 0; ni < 4; ++ni)                                          \
        acc[mi][ni] = MFMA16(af[mi], bfv[ni], acc[mi][ni]);                   \
    __builtin_amdgcn_s_setprio(0);                                            \
  } while (0)

  for (int t = 0; t < nt - 3; ++t) GITER(t, "8", true);
  GITER(nt - 3, "8", false);   // 12 outstanding -> drain tile nt-3
  GITER(nt - 2, "4", false);   // 8 outstanding  -> drain tile nt-2
  GITER(nt - 1, "0", false);   // 4 outstanding  -> drain tile nt-1
#undef GITER

  // Epilogue (register-only; no barrier needed).
  const int rg = lg * 4;
#pragma unroll
  for (int ni = 0; ni < 4; ++ni) {
    const int col = colBase + wn64 + ni * 16 + lr;
    const float bv = bias ? bias[col] : 0.0f;
#pragma unroll
    for (int mi = 0; mi < 8; ++mi) {
#pragma unroll
      for (int r = 0; r < 4; ++r) {
        const size_t row = rowBase + wr128 + mi * 16 + rg + r;
        const float val = acc[mi][ni][r] + bv;
        if constexpr (std::is_same_v<OutT, float>) C[row * (size_t)N + col] = val;
        else                                       C[row * (size_t)N + col] = f2b(val);
      }
    }
  }
}

// ---------------------------------------------------------------------------
// Attention pass 1 (yz half): block = (i,b,a,h). 64 queries j, 64 keys k
// (same a, second spatial axis). Writes unnormalized O1 (bf16) + m1,l1 (fp32).
// ---------------------------------------------------------------------------
__global__ __launch_bounds__(256) void attn_yz(
    const unsigned short* __restrict__ Q,
    const unsigned short* __restrict__ Kx,
    const unsigned short* __restrict__ Vx,
    unsigned short* __restrict__ O1,
    float* __restrict__ m1s, float* __restrict__ l1s)
{
  __shared__ __attribute__((aligned(16))) unsigned short Qs[4096], Ks[4096], Vs[4096], Ps[4096];

  const int bid = blockIdx.x;
  const int h = bid & 15;
  const int a = (bid >> 4) & 63;
  const int b = (bid >> 10) & 7;
  const int i = bid >> 13;
  const int i1 = (i + 1) % 3;

  const size_t qoff = ((size_t)((b * 3 + i) * 4096 + a * 64)) * 1024 + h * 64;
  const size_t koff = ((size_t)((b * 3 + i1) * 4096 + a * 64)) * 1024 + h * 64;

  const int tid = threadIdx.x;
#pragma unroll
  for (int it = 0; it < 2; ++it) {
    const int idx = it * 2048 + tid * 8;
    const int row = idx >> 6, col = idx & 63;
    const int d = swz(row, col);
    *(bf16x8*)&Qs[d] = *(const bf16x8*)(Q + qoff + (size_t)row * 1024 + col);
    *(bf16x8*)&Ks[d] = *(const bf16x8*)(Kx + koff + (size_t)row * 1024 + col);
    *(bf16x8*)&Vs[d] = *(const bf16x8*)(Vx + koff + (size_t)row * 1024 + col);
  }
  __syncthreads();

  const int lane = tid & 63;
  const int w  = tid >> 6;
  const int lr = lane & 15;
  const int lg = lane >> 4;

  // S = Q @ K^T ; wave w owns query rows j = w*16..w*16+15
  f32x4 sa[4] = {};
  {
    const bf16x8 aq0 = *(const bf16x8*)&Qs[swz(w * 16 + lr, lg * 8)];
    const bf16x8 aq1 = *(const bf16x8*)&Qs[swz(w * 16 + lr, 32 + lg * 8)];
#pragma unroll
    for (int nf = 0; nf < 4; ++nf) {
      const bf16x8 bk0 = *(const bf16x8*)&Ks[swz(nf * 16 + lr, lg * 8)];
      const bf16x8 bk1 = *(const bf16x8*)&Ks[swz(nf * 16 + lr, 32 + lg * 8)];
      sa[nf] = MFMA16(aq0, bk0, sa[nf]);
      sa[nf] = MFMA16(aq1, bk1, sa[nf]);
    }
  }

  const float scale = 0.125f;
  float m[4], ls[4];
#pragma unroll
  for (int r = 0; r < 4; ++r) {
#pragma unroll
    for (int nf = 0; nf < 4; ++nf) sa[nf][r] *= scale;
    float v = fmaxf(fmaxf(sa[0][r], sa[1][r]), fmaxf(sa[2][r], sa[3][r]));
    v = fmaxf(v, __shfl_xor(v, 1));
    v = fmaxf(v, __shfl_xor(v, 2));
    v = fmaxf(v, __shfl_xor(v, 4));
    v = fmaxf(v, __shfl_xor(v, 8));
    m[r] = v;
    float s = 0.0f;
#pragma unroll
    for (int nf = 0; nf < 4; ++nf) { const float p = __expf(sa[nf][r] - v); sa[nf][r] = p; s += p; }
    s += __shfl_xor(s, 1);
    s += __shfl_xor(s, 2);
    s += __shfl_xor(s, 4);
    s += __shfl_xor(s, 8);
    ls[r] = s;
  }

#pragma unroll
  for (int nf = 0; nf < 4; ++nf)
#pragma unroll
    for (int r = 0; r < 4; ++r)
      Ps[swz(w * 16 + lg * 4 + r, nf * 16 + lr)] = f2b(sa[nf][r]);

  if (lr == 0) {
    const size_t sb = ((size_t)(i * 8 + b) * 16 + h) * 4096 + a * 64 + w * 16 + lg * 4;
#pragma unroll
    for (int r = 0; r < 4; ++r) { m1s[sb + r] = m[r]; l1s[sb + r] = ls[r]; }
  }
  __syncthreads();

  // O1u = P @ V
  f32x4 oa[4] = {};
#pragma unroll
  for (int ks = 0; ks < 2; ++ks) {
    const bf16x8 ap = *(const bf16x8*)&Ps[swz(w * 16 + lr, ks * 32 + lg * 8)];
#pragma unroll
    for (int df = 0; df < 4; ++df) {
      bf16x8 bv;
#pragma unroll
      for (int e = 0; e < 8; ++e)
        bv[e] = (short)Vs[swz(ks * 32 + lg * 8 + e, df * 16 + lr)];
      oa[df] = MFMA16(ap, bv, oa[df]);
    }
  }

  const size_t ob = ((size_t)(i * 8 + b) * 4096 + a * 64) * 1024 + h * 64;
#pragma unroll
  for (int df = 0; df < 4; ++df)
#pragma unroll
    for (int r = 0; r < 4; ++r)
      O1[ob + (size_t)(w * 16 + lg * 4 + r) * 1024 + df * 16 + lr] = f2b(oa[df][r]);
}

// ---------------------------------------------------------------------------
// Attention pass 2 (zx half, keys along first spatial axis at fixed j)
// + online-softmax combine in place in O1.
// ---------------------------------------------------------------------------
__global__ __launch_bounds__(256) void attn_zx(
    const unsigned short* __restrict__ Q,
    const unsigned short* __restrict__ Kx,
    const unsigned short* __restrict__ Vx,
    unsigned short* __restrict__ O1,
    const float* __restrict__ m1s, const float* __restrict__ l1s)
{
  __shared__ __attribute__((aligned(16))) unsigned short Qs[4096], Ks[4096], Vs[4096], Ps[4096];

  const int bid = blockIdx.x;
  const int j = bid & 63;
  const int h = (bid >> 6) & 15;
  const int b = (bid >> 10) & 7;
  const int i = bid >> 13;
  const int i2 = (i + 2) % 3;

  const size_t qoff = ((size_t)(b * 3 + i) * 4096 + j) * 1024 + h * 64;
  const size_t koff = ((size_t)(b * 3 + i2) * 4096 + j) * 1024 + h * 64;
  const size_t rstride = 65536;  // 64 rows * 1024 cols

  const int tid = threadIdx.x;
#pragma unroll
  for (int it = 0; it < 2; ++it) {
    const int idx = it * 2048 + tid * 8;
    const int row = idx >> 6, col = idx & 63;
    const int d = swz(row, col);
    *(bf16x8*)&Qs[d] = *(const bf16x8*)(Q + qoff + (size_t)row * rstride + col);
    *(bf16x8*)&Ks[d] = *(const bf16x8*)(Kx + koff + (size_t)row * rstride + col);
    *(bf16x8*)&Vs[d] = *(const bf16x8*)(Vx + koff + (size_t)row * rstride + col);
  }
  __syncthreads();

  const int lane = tid & 63;
  const int w  = tid >> 6;
  const int lr = lane & 15;
  const int lg = lane >> 4;

  f32x4 sa[4] = {};
  {
    const bf16x8 aq0 = *(const bf16x8*)&Qs[swz(w * 16 + lr, lg * 8)];
    const bf16x8 aq1 = *(const bf16x8*)&Qs[swz(w * 16 + lr, 32 + lg * 8)];
#pragma unroll
    for (int nf = 0; nf < 4; ++nf) {
      const bf16x8 bk0 = *(const bf16x8*)&Ks[swz(nf * 16 + lr, lg * 8)];
      const bf16x8 bk1 = *(const bf16x8*)&Ks[swz(nf * 16 + lr, 32 + lg * 8)];
      sa[nf] = MFMA16(aq0, bk0, sa[nf]);
      sa[nf] = MFMA16(aq1, bk1, sa[nf]);
    }
  }

  const float scale = 0.125f;
  float m[4], ls[4];
#pragma unroll
  for (int r = 0; r < 4; ++r) {
#pragma unroll
    for (int nf = 0; nf < 4; ++nf) sa[nf][r] *= scale;
    float v = fmaxf(fmaxf(sa[0][r], sa[1][r]), fmaxf(sa[2][r], sa[3][r]));
    v = fmaxf(v, __shfl_xor(v, 1));
    v = fmaxf(v, __shfl_xor(v, 2));
    v = fmaxf(v, __shfl_xor(v, 4));
    v = fmaxf(v, __shfl_xor(v, 8));
    m[r] = v;
    float s = 0.0f;
#pragma unroll
    for (int nf = 0; nf < 4; ++nf) { const float p = __expf(sa[nf][r] - v); sa[nf][r] = p; s += p; }
    s += __shfl_xor(s, 1);
    s += __shfl_xor(s, 2);
    s += __shfl_xor(s, 4);
    s += __shfl_xor(s, 8);
    ls[r] = s;
  }

  float c1[4], c2[4], rden[4];
  const size_t sb = ((size_t)(i * 8 + b) * 16 + h) * 4096 + j;
#pragma unroll
  for (int r = 0; r < 4; ++r) {
    const int arow = w * 16 + lg * 4 + r;
    const float mm1 = m1s[sb + (size_t)arow * 64];
    const float ll1 = l1s[sb + (size_t)arow * 64];
    const float mm = fmaxf(mm1, m[r]);
    const float e1 = __expf(mm1 - mm);
    const float e2 = __expf(m[r] - mm);
    c1[r] = e1; c2[r] = e2;
    rden[r] = 1.0f / (e1 * ll1 + e2 * ls[r]);
  }

#pragma unroll
  for (int nf = 0; nf < 4; ++nf)
#pragma unroll
    for (int r = 0; r < 4; ++r)
      Ps[swz(w * 16 + lg * 4 + r, nf * 16 + lr)] = f2b(sa[nf][r]);
  __syncthreads();

  f32x4 oa[4] = {};
#pragma unroll
  for (int ks = 0; ks < 2; ++ks) {
    const bf16x8 ap = *(const bf16x8*)&Ps[swz(w * 16 + lr, ks * 32 + lg * 8)];
#pragma unroll
    for (int df = 0; df < 4; ++df) {
      bf16x8 bv;
#pragma unroll
      for (int e = 0; e < 8; ++e)
        bv[e] = (short)Vs[swz(ks * 32 + lg * 8 + e, df * 16 + lr)];
      oa[df] = MFMA16(ap, bv, oa[df]);
    }
  }

  const size_t ob = ((size_t)(i * 8 + b) * 4096 + j) * 1024 + h * 64;
#pragma unroll
  for (int df = 0; df < 4; ++df)
#pragma unroll
    for (int r = 0; r < 4; ++r) {
      const size_t addr = ob + (size_t)(w * 16 + lg * 4 + r) * rstride + df * 16 + lr;
      const float o1v = b2f(O1[addr]);
      O1[addr] = f2b((c1[r] * o1v + c2[r] * oa[df][r]) * rden[r]);
    }
}

// ---------------------------------------------------------------------------
extern "C" void kernel_launch(void* const* d_in, const int* in_sizes, int n_in,
                              void* d_out, int out_size, void* d_ws, size_t ws_size,
                              hipStream_t stream)
{
  const float* x  = (const float*)d_in[0];
  const float* wq = (const float*)d_in[1];
  const float* wk = (const float*)d_in[2];
  const float* wv = (const float*)d_in[3];
  const float* wp = (const float*)d_in[4];
  const float* bp = (const float*)d_in[5];

  const int M = 98304, N = 1024, K = 1024;
  const size_t SLAB = 201326592ull;   // 98304*1024*2 bytes (bf16 slab)
  const size_t STAT = 6291456ull;     // 3*8*16*4096 floats

  char* ws = (char*)d_ws;
  unsigned short* xb  = (unsigned short*)(ws);            // converted x; reused as O1 after QKV
  unsigned short* Kb  = (unsigned short*)(ws + SLAB);
  unsigned short* Vb  = (unsigned short*)(ws + 2 * SLAB);
  float* m1s          = (float*)(ws + 3 * SLAB);
  float* l1s          = (float*)(ws + 3 * SLAB + STAT);
  unsigned short* wqb = (unsigned short*)(ws + 3 * SLAB + 2 * STAT);
  unsigned short* wkb = wqb + 1048576;
  unsigned short* wvb = wkb + 1048576;
  unsigned short* wpb = wvb + 1048576;
  unsigned short* Qb  = (unsigned short*)d_out;  // bf16 Q scratch in fp32 d_out; dead before final write
  unsigned short* O1  = xb;                      // x slab dead after the three QKV GEMMs

  dim3 blk(256);
  cvt_f32_bf16<<<dim3(4096), blk, 0, stream>>>(x,  xb,  (long long)M * 1024);
  cvt_f32_bf16<<<dim3(512),  blk, 0, stream>>>(wq, wqb, 1048576);
  cvt_f32_bf16<<<dim3(512),  blk, 0, stream>>>(wk, wkb, 1048576);
  cvt_f32_bf16<<<dim3(512),  blk, 0, stream>>>(wv, wvb, 1048576);
  cvt_f32_bf16<<<dim3(512),  blk, 0, stream>>>(wp, wpb, 1048576);

  dim3 gg((M / 256) * (N / 256));   // 1536 blocks, % 8 == 0 (bijective XCD remap)
  dim3 gblk(512);
  gemm_bt<unsigned short><<<gg, gblk, 0, stream>>>(xb, wqb, (const float*)nullptr, Qb, M, N, K);
  gemm_bt<unsigned short><<<gg, gblk, 0, stream>>>(xb, wkb, (const float*)nullptr, Kb, M, N, K);
  gemm_bt<unsigned short><<<gg, gblk, 0, stream>>>(xb, wvb, (const float*)nullptr, Vb, M, N, K);
  attn_yz<<<dim3(24576), blk, 0, stream>>>(Qb, Kb, Vb, O1, m1s, l1s);
  attn_zx<<<dim3(24576), blk, 0, stream>>>(Qb, Kb, Vb, O1, m1s, l1s);
  gemm_bt<float><<<gg, gblk, 0, stream>>>(O1, wpb, bp, (float*)d_out, M, N, K);
}